// Round 3
// baseline (201.930 us; speedup 1.0000x reference)
//
#include <hip/hip_runtime.h>

// Zero-phase bandpass FIR = one 8191-tap correlation with the kernel
// autocorrelation g, as an implicit-Toeplitz MFMA GEMM.
//   out[t] = sum_s g[s] * xe[t + s],  g = autocorr(k) (bf16, hi only)
// Round 8: explicit software pipeline. A-frags register-ping-ponged one
// step ahead; chunk body fully unrolled (compile-time Qr); staging issued
// AFTER step-1's A-prefetch so mid-chunk A-waits are counted vmcnt that
// do NOT drain the (FIFO-older) staging; boundary vmcnt(0) is then free.
// Keeps R7's 512-thr / 8-wave / 4-row x 4-mt / qh-split structure.

#define T_LEN   131072
#define XE_LEN  139776
#define XE_U4   (XE_LEN / 8)      // 17472 uint4 per row
#define NCHUNK  312               // A chunks: table P in [0,312), p = P-24
#define QQ      72                // Q-steps per wave (per Q-quarter)
#define NCH     9                 // chunks per wave

typedef float  f32x4  __attribute__((ext_vector_type(4)));
typedef __bf16 bf16x8 __attribute__((ext_vector_type(8)));

// ---------- ws layout (bytes) ----------
#define WS_KZ   0                 // 12288 floats (zero-padded k)
#define WS_G    49152             // 8192 floats  (autocorrelation)
#define WS_AHI  81920             // 312*512 bf16 Toeplitz frags = 319488 B
#define WS_XE   401408            // 32*139776 bf16 padded signal
#define WS_END  9347072

__device__ __forceinline__ void gload_lds16(const uint4* g, uint4* lds) {
  __builtin_amdgcn_global_load_lds(
      (const __attribute__((address_space(1))) unsigned int*)g,
      (__attribute__((address_space(3))) unsigned int*)lds, 16, 0, 0);
}

// K1: g[s] += partial over 256-long i-chunk; grid (32, 16).
__global__ void k_autocorr(const float* __restrict__ k,
                           const float* __restrict__ kz,
                           float* __restrict__ g) {
  int s = blockIdx.x * 256 + threadIdx.x;
  int i0 = blockIdx.y * 256;
  const float* kk  = k + i0;
  const float* kzs = kz + (8191 - s) + i0;   // 4-B aligned only
  float a0 = 0.f, a1 = 0.f, a2 = 0.f, a3 = 0.f;
  #pragma unroll 4
  for (int i = 0; i < 256; i += 4) {
    float4 kv = *(const float4*)(kk + i);
    float4 zv;
    __builtin_memcpy(&zv, kzs + i, 16);
    a0 = fmaf(kv.x, zv.x, a0);
    a1 = fmaf(kv.y, zv.y, a1);
    a2 = fmaf(kv.z, zv.z, a2);
    a3 = fmaf(kv.w, zv.w, a3);
  }
  atomicAdd(&g[s], (a0 + a1) + (a2 + a3));
}

// K2: Toeplitz A fragments, fragment-ordered (chunk P, lane l, 8 bf16).
// A_p[i][k] = gpad[32p + k - i], lane l: i = l&15, k = (l>>4)*8 + jj.
__global__ void k_build_afrag(const float* __restrict__ g,
                              __bf16* __restrict__ Ahi) {
  int P = blockIdx.x;
  int t = threadIdx.x;
  int l = t >> 2;
  int jj0 = (t & 3) * 2;
  int q = l >> 4, i = l & 15;
  int p = P - 24;
  #pragma unroll
  for (int u = 0; u < 2; ++u) {
    int jj = jj0 + u;
    int s = 32 * p + 8 * q + jj - i;
    float val = (s >= 0 && s <= 8190) ? g[s] : 0.0f;
    Ahi[P * 512 + l * 8 + jj] = (__bf16)val;
  }
}

// K0 (fused): xe[row][w] = bf16( X(w-4095) ), reflect in [-2048, T+2048),
// else 0. blockIdx.y==0 additionally builds kz (zero-padded k) and zeros g.
__global__ void k_build_xe(const float* __restrict__ x, __bf16* __restrict__ xe,
                           const float* __restrict__ k, float* __restrict__ kz,
                           float* __restrict__ g) {
  if (blockIdx.y == 0) {           // fused former k_build_kz
    int m = blockIdx.x * 256 + threadIdx.x;
    if (m < 12288) {
      int i = m - 4096;
      kz[m] = (i >= 0 && i < 4096) ? k[i] : 0.0f;
    }
    if (m < 8192) g[m] = 0.0f;
  }
  int e0 = (blockIdx.x * 256 + threadIdx.x) * 8;
  int row = blockIdx.y;
  if (e0 >= XE_LEN) return;
  const float* xr = x + (size_t)row * T_LEN;
  int v0 = e0 - 4095;
  bf16x8 outv;
  if (v0 >= 0 && v0 <= T_LEN - 8) {
    float4 f0, f1;
    __builtin_memcpy(&f0, xr + v0, 16);
    __builtin_memcpy(&f1, xr + v0 + 4, 16);
    outv[0] = (__bf16)f0.x; outv[1] = (__bf16)f0.y;
    outv[2] = (__bf16)f0.z; outv[3] = (__bf16)f0.w;
    outv[4] = (__bf16)f1.x; outv[5] = (__bf16)f1.y;
    outv[6] = (__bf16)f1.z; outv[7] = (__bf16)f1.w;
  } else {
    #pragma unroll
    for (int u = 0; u < 8; ++u) {
      int v = v0 + u;
      float val = 0.0f;
      if (v >= -2048 && v < T_LEN + 2048) {
        int v2 = v < 0 ? -v : v;
        v2 = v2 >= T_LEN ? 2 * T_LEN - 2 - v2 : v2;
        val = xr[v2];
      }
      outv[u] = (__bf16)val;
    }
  }
  ((uint4*)(xe + (size_t)row * XE_LEN))[e0 >> 3] =
      __builtin_bit_cast(uint4, outv);
}

// One pipelined Q-step (Qr is a compile-time literal). AC holds this
// step's 4 A-frags (prefetched last step); AN receives next step's.
// Issue order inside a step: B ds_reads, A-prefetch (global), MFMA burst.
// The compiler then emits counted lgkmcnt before the MFMAs and counted
// vmcnt for AC (queue: [AC(done), AN, (stage)]) -- loads fly under MFMAs.
#define STEP(Qr, AC, AN)                                                   \
  {                                                                        \
    bf16x8 Bv[4];                                                          \
    _Pragma("unroll")                                                      \
    for (int r = 0; r < 4; ++r)                                            \
      Bv[r] = __builtin_bit_cast(bf16x8, bw[(r << 6) + 4 * (Qr)]);         \
    if ((Qr) < 7) {              /* prefetch A for step Qr+1 */            \
      _Pragma("unroll")                                                    \
      for (int mt = 0; mt < 4; ++mt)                                       \
        AN[mt] = __builtin_bit_cast(bf16x8, Acb[((Qr) + 1 - 8 * mt) * 64]);\
    } else if (ch + 1 < NCH) {   /* next chunk's step 0 (Q+8) */           \
      _Pragma("unroll")                                                    \
      for (int mt = 0; mt < 4; ++mt)                                       \
        AN[mt] = __builtin_bit_cast(bf16x8, Acb[(8 - 8 * mt) * 64]);       \
    }                                                                      \
    __builtin_amdgcn_s_setprio(1);                                         \
    _Pragma("unroll")                                                      \
    for (int r = 0; r < 4; ++r)                                            \
      _Pragma("unroll")                                                    \
      for (int mt = 0; mt < 4; ++mt)                                       \
        acc[r][mt] = __builtin_amdgcn_mfma_f32_16x16x32_bf16(              \
            AC[mt], Bv[r], acc[r][mt], 0, 0, 0);                           \
    __builtin_amdgcn_s_setprio(0);                                         \
  }

// Main: 512 threads = 8 waves = 2 row-groups (4 rows) x 4 Q-quarters.
// Wave (rg,qh): partial over Q in [72qh, 72qh+72) of 4 rows, 1024-t span.
// Per Q-step: 4 A global loads (prefetched 1 step ahead into ping-pong
// regs), 4 ds_read_b128, 16 MFMA. B staged chunk-wise (8 Qs) by async
// global_load_lds into a wave-private double buffer; staging issued after
// step 1 so A-waits stay counted (vmcnt FIFO). 2 blocks/CU, 16 waves/CU.
__global__ __launch_bounds__(512, 4) void k_fir_mfma(
    const uint4* __restrict__ xeu, const uint4* __restrict__ Ahi,
    float* __restrict__ out) {
  __shared__ uint4 sbB[4096];      // 64 KB: wave*512 + buf*256 + row*64

  const int tid = threadIdx.x;
  const int w   = tid >> 6;                  // 8 waves
  const int l   = tid & 63;
  const int q   = l >> 4;
  const int n   = l & 15;
  const int qh  = w & 3;                     // Q-quarter
  const int rg  = w >> 2;                    // row-group (4 rows)

  // XCD swizzle: 512 blocks, 8 XCDs -> 64 contiguous flat ids per XCD.
  const int orig = blockIdx.x;
  const int flat = (orig & 7) * 64 + (orig >> 3);
  const int bx   = flat & 127;
  const int by   = flat >> 7;

  const int t0     = bx << 10;               // 1024 outputs per block
  const int brbase = by << 3;                // block's 8 rows
  const int wrbase = brbase + (rg << 2);     // this wave's 4 rows
  const int Qbeg   = qh * QQ;
  const int lofs   = q + 2 * n;              // uint4 offset in B window

  // per-lane global base for staging (lane l covers uint4 slot l of a row)
  const uint4* gbase = xeu + (size_t)wrbase * XE_U4 + (t0 >> 3) + 4 * Qbeg + l;
  uint4* sw = sbB + (w << 9);                // 512 uint4 per wave
  const bf16x8* Ahi8 = (const bf16x8*)Ahi;

  f32x4 acc[4][4];
  #pragma unroll
  for (int r = 0; r < 4; ++r)
    #pragma unroll
    for (int m = 0; m < 4; ++m) acc[r][m] = (f32x4){0.f, 0.f, 0.f, 0.f};

  // prologue: stage chunk 0 into buf 0; prefetch step-0 A; drain all.
  #pragma unroll
  for (int r = 0; r < 4; ++r)
    gload_lds16(gbase + (size_t)r * XE_U4, sw + (r << 6));
  bf16x8 A0[4], A1[4];
  #pragma unroll
  for (int mt = 0; mt < 4; ++mt)
    A0[mt] = __builtin_bit_cast(bf16x8, Ahi8[(size_t)(Qbeg + 24 - 8 * mt) * 64 + l]);
  asm volatile("s_waitcnt vmcnt(0)" ::: "memory");

  int buf = 0;
  for (int ch = 0; ch < NCH; ++ch) {         // NOT unrolled (I-cache)
    const uint4*  bw  = sw + (buf << 8) + lofs;
    const bf16x8* Acb = Ahi8 + (size_t)(Qbeg + ch * 8 + 24) * 64 + l;

    STEP(0, A0, A1)
    STEP(1, A1, A0)

    if (ch + 1 < NCH) {          // async-stage next chunk (FIFO-after A(2))
      uint4* dst = sw + ((buf ^ 1) << 8);
      const uint4* src = gbase + ((ch + 1) << 5);
      #pragma unroll
      for (int r = 0; r < 4; ++r)
        gload_lds16(src + (size_t)r * XE_U4, dst + (r << 6));
    }

    STEP(2, A0, A1)
    STEP(3, A1, A0)
    STEP(4, A0, A1)
    STEP(5, A1, A0)
    STEP(6, A0, A1)
    STEP(7, A1, A0)

    if (ch + 1 < NCH) {
      asm volatile("s_waitcnt vmcnt(0)" ::: "memory");   // stage 6 steps old
      buf ^= 1;
    }
  }

  // ---- combine 4 qh partials per row-group in LDS (phased mt slices) ----
  __syncthreads();
  float* C = (float*)sbB;                    // 8 rows x 1024 t (32 KB)
  const int co = (q << 2) + (n << 4);        // C/D: col=n, row=(q*4+reg)
  #pragma unroll
  for (int ph = 0; ph < 4; ++ph) {
    const int mt = (qh + ph) & 3;
    float* cp = C + ((rg << 2) << 10) + (mt << 8) + co;
    if (ph == 0) {
      #pragma unroll
      for (int r = 0; r < 4; ++r)
        *(f32x4*)(cp + (r << 10)) = acc[r][mt];
    } else {
      #pragma unroll
      for (int r = 0; r < 4; ++r) {
        f32x4 v = *(f32x4*)(cp + (r << 10));
        v += acc[r][mt];
        *(f32x4*)(cp + (r << 10)) = v;
      }
    }
    __syncthreads();
  }

  // ---- coalesced store: 2048 f32x4, 512 threads x 4 ----
  #pragma unroll
  for (int u = 0; u < 4; ++u) {
    const int idx = tid + (u << 9);
    f32x4 v = ((f32x4*)C)[idx];
    const int row = idx >> 8;                // 256 f32x4 per row
    const int tc  = (idx & 255) << 2;
    *(f32x4*)(out + (size_t)(brbase + row) * T_LEN + t0 + tc) = v;
  }
}

extern "C" void kernel_launch(void* const* d_in, const int* in_sizes, int n_in,
                              void* d_out, int out_size, void* d_ws, size_t ws_size,
                              hipStream_t stream) {
  const float* x = (const float*)d_in[0];
  const float* k = (const float*)d_in[1];
  float* out = (float*)d_out;
  char* ws = (char*)d_ws;
  if (ws_size < (size_t)WS_END) return;

  float*  kz  = (float*)(ws + WS_KZ);
  float*  g   = (float*)(ws + WS_G);
  __bf16* Ahi = (__bf16*)(ws + WS_AHI);
  __bf16* xe  = (__bf16*)(ws + WS_XE);

  k_build_xe<<<dim3((XE_LEN / 8 + 255) / 256, 32), dim3(256), 0, stream>>>(
      x, xe, k, kz, g);
  k_autocorr<<<dim3(32, 16), dim3(256), 0, stream>>>(k, kz, g);
  k_build_afrag<<<dim3(NCHUNK), dim3(256), 0, stream>>>(g, Ahi);
  k_fir_mfma<<<dim3(512), dim3(512), 0, stream>>>(
      (const uint4*)xe, (const uint4*)Ahi, out);
}

// Round 4
// 149.742 us; speedup vs baseline: 1.3485x; 1.3485x over previous
//
#include <hip/hip_runtime.h>

// Zero-phase bandpass FIR = one 8191-tap correlation with the kernel
// autocorrelation g, as an implicit-Toeplitz MFMA GEMM.
//   out[t] = sum_s g[s] * xe[t + s],  g = autocorr(k) (bf16, hi only)
// Round 9: A-stream eliminated. Toeplitz identity frag(Q,mt)=frag(Q+8,mt+1)
// -> 32-frag register ring (G0..G3), ONE fresh A load/step (was 4), fed
// directly from a 20 KB L1-resident zero-padded bf16 gpad (2 byte-shifted
// copies for 4-B alignment) instead of the 312 KB fragment table.
// k_build_afrag replaced by trivial k_build_gpad. Ring costs 128 VGPR ->
// launch_bounds(512,2), 8 waves/CU; LDS B-path (4 ds_read/step) is the
// new design limiter at ~28K cyc/CU.

#define T_LEN   131072
#define XE_LEN  139776
#define XE_U4   (XE_LEN / 8)      // 17472 uint4 per row
#define QQ      72                // Q-steps per wave (per Q-quarter)
#define NCH     9                 // chunks per wave
#define GP_STRIDE 24576           // bytes per gpad copy

typedef float  f32x4  __attribute__((ext_vector_type(4)));
typedef __bf16 bf16x8 __attribute__((ext_vector_type(8)));

// ---------- ws layout (bytes) ----------
#define WS_KZ   0                 // 12288 floats (zero-padded k)
#define WS_G    49152             // 8192 floats  (autocorrelation)
#define WS_GP   81920             // 2 copies x 24576 B bf16 gpad
#define WS_XE   131072            // 32*139776 bf16 padded signal
#define WS_END  9347072

__device__ __forceinline__ void gload_lds16(const uint4* g, uint4* lds) {
  __builtin_amdgcn_global_load_lds(
      (const __attribute__((address_space(1))) unsigned int*)g,
      (__attribute__((address_space(3))) unsigned int*)lds, 16, 0, 0);
}

// K1: g[s] += partial over 256-long i-chunk; grid (32, 16).
__global__ void k_autocorr(const float* __restrict__ k,
                           const float* __restrict__ kz,
                           float* __restrict__ g) {
  int s = blockIdx.x * 256 + threadIdx.x;
  int i0 = blockIdx.y * 256;
  const float* kk  = k + i0;
  const float* kzs = kz + (8191 - s) + i0;   // 4-B aligned only
  float a0 = 0.f, a1 = 0.f, a2 = 0.f, a3 = 0.f;
  #pragma unroll 4
  for (int i = 0; i < 256; i += 4) {
    float4 kv = *(const float4*)(kk + i);
    float4 zv;
    __builtin_memcpy(&zv, kzs + i, 16);
    a0 = fmaf(kv.x, zv.x, a0);
    a1 = fmaf(kv.y, zv.y, a1);
    a2 = fmaf(kv.z, zv.z, a2);
    a3 = fmaf(kv.w, zv.w, a3);
  }
  atomicAdd(&g[s], (a0 + a1) + (a2 + a3));
}

// K2': gpad[e] = bf16(g[e]) for e in [0,8190], else 0, over e in
// [-1024, 10240); TWO copies byte-shifted by GP_STRIDE+2 so every lane's
// 16-B A-frag read (start element 32(F-24)+8q-n, parity = n&1) is 4-B
// aligned. Grid (44), 256 thr.
__global__ void k_build_gpad(const float* __restrict__ g,
                             char* __restrict__ gp) {
  int idx = blockIdx.x * 256 + threadIdx.x;   // [0, 11264)
  int e = idx - 1024;
  float v = (e >= 0 && e <= 8190) ? g[e] : 0.0f;
  __bf16 b = (__bf16)v;
  *(__bf16*)(gp + 2 * idx) = b;
  *(__bf16*)(gp + GP_STRIDE + 2 + 2 * idx) = b;
}

// K0 (fused): xe[row][w] = bf16( X(w-4095) ), reflect in [-2048, T+2048),
// else 0. blockIdx.y==0 additionally builds kz (zero-padded k) and zeros g.
__global__ void k_build_xe(const float* __restrict__ x, __bf16* __restrict__ xe,
                           const float* __restrict__ k, float* __restrict__ kz,
                           float* __restrict__ g) {
  if (blockIdx.y == 0) {           // fused former k_build_kz
    int m = blockIdx.x * 256 + threadIdx.x;
    if (m < 12288) {
      int i = m - 4096;
      kz[m] = (i >= 0 && i < 4096) ? k[i] : 0.0f;
    }
    if (m < 8192) g[m] = 0.0f;
  }
  int e0 = (blockIdx.x * 256 + threadIdx.x) * 8;
  int row = blockIdx.y;
  if (e0 >= XE_LEN) return;
  const float* xr = x + (size_t)row * T_LEN;
  int v0 = e0 - 4095;
  bf16x8 outv;
  if (v0 >= 0 && v0 <= T_LEN - 8) {
    float4 f0, f1;
    __builtin_memcpy(&f0, xr + v0, 16);
    __builtin_memcpy(&f1, xr + v0 + 4, 16);
    outv[0] = (__bf16)f0.x; outv[1] = (__bf16)f0.y;
    outv[2] = (__bf16)f0.z; outv[3] = (__bf16)f0.w;
    outv[4] = (__bf16)f1.x; outv[5] = (__bf16)f1.y;
    outv[6] = (__bf16)f1.z; outv[7] = (__bf16)f1.w;
  } else {
    #pragma unroll
    for (int u = 0; u < 8; ++u) {
      int v = v0 + u;
      float val = 0.0f;
      if (v >= -2048 && v < T_LEN + 2048) {
        int v2 = v < 0 ? -v : v;
        v2 = v2 >= T_LEN ? 2 * T_LEN - 2 - v2 : v2;
        val = xr[v2];
      }
      outv[u] = (__bf16)val;
    }
  }
  ((uint4*)(xe + (size_t)row * XE_LEN))[e0 >> 3] =
      __builtin_bit_cast(uint4, outv);
}

// One chunk (8 Q-steps), ring roles GA=oldest(mt3) .. GD=newest(mt0).
// Per step: 4 B ds_read_b128 (staged LDS), copy-out old GA[Qr] (mt3),
// overwrite GA[Qr] with fresh frag F = Qbeg+CH*8+32+Qr from L1-resident
// gpad (consumed 8 steps later as next chunk's mt0 -> latency-free),
// 16 MFMA. Staging of chunk CH+1 issued at top; vmcnt(0) drain at end
// (staging is 8 steps old by then).
#define CHUNK(CH, BUF, GA, GB, GC, GD, DO_STAGE)                           \
  {                                                                        \
    if (DO_STAGE) {                                                        \
      uint4* dst = sw + ((BUF ^ 1) << 8);                                  \
      const uint4* src = gbase + (((CH) + 1) << 5);                        \
      _Pragma("unroll")                                                    \
      for (int r = 0; r < 4; ++r)                                          \
        gload_lds16(src + (size_t)r * XE_U4, dst + (r << 6));              \
    }                                                                      \
    const uint4* bw = sw + ((BUF) << 8) + lofs;                            \
    _Pragma("unroll")                                                      \
    for (int Qr = 0; Qr < 8; ++Qr) {                                       \
      bf16x8 Bv[4];                                                        \
      _Pragma("unroll")                                                    \
      for (int r = 0; r < 4; ++r)                                          \
        Bv[r] = __builtin_bit_cast(bf16x8, bw[(r << 6) + 4 * Qr]);         \
      bf16x8 a3 = GA[Qr], a2 = GB[Qr], a1 = GC[Qr], a0 = GD[Qr];           \
      uint4 tmp;                                                           \
      __builtin_memcpy(&tmp,                                               \
          laneA + ((size_t)(Qbeg + (CH) * 8 + 32 + Qr) << 6), 16);         \
      GA[Qr] = __builtin_bit_cast(bf16x8, tmp);                            \
      __builtin_amdgcn_s_setprio(1);                                       \
      _Pragma("unroll")                                                    \
      for (int r = 0; r < 4; ++r) {                                        \
        acc[r][0] = __builtin_amdgcn_mfma_f32_16x16x32_bf16(a0, Bv[r],     \
                                                            acc[r][0], 0, 0, 0); \
        acc[r][1] = __builtin_amdgcn_mfma_f32_16x16x32_bf16(a1, Bv[r],     \
                                                            acc[r][1], 0, 0, 0); \
        acc[r][2] = __builtin_amdgcn_mfma_f32_16x16x32_bf16(a2, Bv[r],     \
                                                            acc[r][2], 0, 0, 0); \
        acc[r][3] = __builtin_amdgcn_mfma_f32_16x16x32_bf16(a3, Bv[r],     \
                                                            acc[r][3], 0, 0, 0); \
      }                                                                    \
      __builtin_amdgcn_s_setprio(0);                                       \
    }                                                                      \
    if (DO_STAGE)                                                          \
      asm volatile("s_waitcnt vmcnt(0)" ::: "memory");                     \
  }

// Main: 512 threads = 8 waves = 2 row-groups (4 rows) x 4 Q-quarters.
// Per Q-step: 1 fresh A load (gpad, L1), 4 ds_read_b128 (B), 16 MFMA.
// Ring G0..G3 rotates roles every chunk (period 4); 9 chunks unrolled.
// 8 waves/CU (launch_bounds(512,2): ring 128 + Bv 16 + acc 64 AGPR fits
// the 256-reg budget). No barriers in the main loop.
__global__ __launch_bounds__(512, 2) void k_fir_mfma(
    const uint4* __restrict__ xeu, const char* __restrict__ gpad,
    float* __restrict__ out) {
  __shared__ uint4 sbB[4096];      // 64 KB: wave*512 + buf*256 + row*64

  const int tid = threadIdx.x;
  const int w   = tid >> 6;                  // 8 waves
  const int l   = tid & 63;
  const int q   = l >> 4;
  const int n   = l & 15;
  const int qh  = w & 3;                     // Q-quarter
  const int rg  = w >> 2;                    // row-group (4 rows)

  // XCD swizzle: 512 blocks, 8 XCDs -> 64 contiguous flat ids per XCD.
  const int orig = blockIdx.x;
  const int flat = (orig & 7) * 64 + (orig >> 3);
  const int bx   = flat & 127;
  const int by   = flat >> 7;

  const int t0     = bx << 10;               // 1024 outputs per block
  const int brbase = by << 3;                // block's 8 rows
  const int wrbase = brbase + (rg << 2);     // this wave's 4 rows
  const int Qbeg   = qh * QQ;
  const int lofs   = q + 2 * n;              // uint4 offset in B window

  // per-lane global base for staging (lane l covers uint4 slot l of a row)
  const uint4* gbase = xeu + (size_t)wrbase * XE_U4 + (t0 >> 3) + 4 * Qbeg + l;
  uint4* sw = sbB + (w << 9);                // 512 uint4 per wave

  // A-frag source: element e0(F) = 32(F-24) + 8q - n, byte = 2(e0+1024)
  // in copy (n&1): laneA + 64F with laneA = copy_base + 16q - 2n + 512.
  const char* laneA = gpad + ((n & 1) ? (GP_STRIDE + 2) : 0)
                      + 16 * q - 2 * n + 512;

  f32x4 acc[4][4];
  #pragma unroll
  for (int r = 0; r < 4; ++r)
    #pragma unroll
    for (int m = 0; m < 4; ++m) acc[r][m] = (f32x4){0.f, 0.f, 0.f, 0.f};

  // prologue: prime ring with frags Qbeg..Qbeg+31; stage chunk 0; drain.
  bf16x8 G0[8], G1[8], G2[8], G3[8];
  #pragma unroll
  for (int j = 0; j < 8; ++j) {
    uint4 u0, u1, u2, u3;
    __builtin_memcpy(&u0, laneA + ((size_t)(Qbeg + j) << 6), 16);
    __builtin_memcpy(&u1, laneA + ((size_t)(Qbeg + 8 + j) << 6), 16);
    __builtin_memcpy(&u2, laneA + ((size_t)(Qbeg + 16 + j) << 6), 16);
    __builtin_memcpy(&u3, laneA + ((size_t)(Qbeg + 24 + j) << 6), 16);
    G0[j] = __builtin_bit_cast(bf16x8, u0);
    G1[j] = __builtin_bit_cast(bf16x8, u1);
    G2[j] = __builtin_bit_cast(bf16x8, u2);
    G3[j] = __builtin_bit_cast(bf16x8, u3);
  }
  #pragma unroll
  for (int r = 0; r < 4; ++r)
    gload_lds16(gbase + (size_t)r * XE_U4, sw + (r << 6));
  asm volatile("s_waitcnt vmcnt(0)" ::: "memory");

  CHUNK(0, 0, G0, G1, G2, G3, 1)
  CHUNK(1, 1, G1, G2, G3, G0, 1)
  CHUNK(2, 0, G2, G3, G0, G1, 1)
  CHUNK(3, 1, G3, G0, G1, G2, 1)
  CHUNK(4, 0, G0, G1, G2, G3, 1)
  CHUNK(5, 1, G1, G2, G3, G0, 1)
  CHUNK(6, 0, G2, G3, G0, G1, 1)
  CHUNK(7, 1, G3, G0, G1, G2, 1)
  CHUNK(8, 0, G0, G1, G2, G3, 0)

  // ---- combine 4 qh partials per row-group in LDS (phased mt slices) ----
  __syncthreads();
  float* C = (float*)sbB;                    // 8 rows x 1024 t (32 KB)
  const int co = (q << 2) + (n << 4);        // C/D: col=n, row=(q*4+reg)
  #pragma unroll
  for (int ph = 0; ph < 4; ++ph) {
    const int mt = (qh + ph) & 3;
    float* cp = C + ((rg << 2) << 10) + (mt << 8) + co;
    if (ph == 0) {
      #pragma unroll
      for (int r = 0; r < 4; ++r)
        *(f32x4*)(cp + (r << 10)) = acc[r][mt];
    } else {
      #pragma unroll
      for (int r = 0; r < 4; ++r) {
        f32x4 v = *(f32x4*)(cp + (r << 10));
        v += acc[r][mt];
        *(f32x4*)(cp + (r << 10)) = v;
      }
    }
    __syncthreads();
  }

  // ---- coalesced store: 2048 f32x4, 512 threads x 4 ----
  #pragma unroll
  for (int u = 0; u < 4; ++u) {
    const int idx = tid + (u << 9);
    f32x4 v = ((f32x4*)C)[idx];
    const int row = idx >> 8;                // 256 f32x4 per row
    const int tc  = (idx & 255) << 2;
    *(f32x4*)(out + (size_t)(brbase + row) * T_LEN + t0 + tc) = v;
  }
}

extern "C" void kernel_launch(void* const* d_in, const int* in_sizes, int n_in,
                              void* d_out, int out_size, void* d_ws, size_t ws_size,
                              hipStream_t stream) {
  const float* x = (const float*)d_in[0];
  const float* k = (const float*)d_in[1];
  float* out = (float*)d_out;
  char* ws = (char*)d_ws;
  if (ws_size < (size_t)WS_END) return;

  float* kz = (float*)(ws + WS_KZ);
  float* g  = (float*)(ws + WS_G);
  char*  gp = ws + WS_GP;
  __bf16* xe = (__bf16*)(ws + WS_XE);

  k_build_xe<<<dim3((XE_LEN / 8 + 255) / 256, 32), dim3(256), 0, stream>>>(
      x, xe, k, kz, g);
  k_autocorr<<<dim3(32, 16), dim3(256), 0, stream>>>(k, kz, g);
  k_build_gpad<<<dim3(44), dim3(256), 0, stream>>>(g, gp);
  k_fir_mfma<<<dim3(512), dim3(512), 0, stream>>>(
      (const uint4*)xe, gp, out);
}

// Round 5
// 148.292 us; speedup vs baseline: 1.3617x; 1.0098x over previous
//
#include <hip/hip_runtime.h>

// Zero-phase bandpass FIR = one 8191-tap correlation with the kernel
// autocorrelation g, as an implicit-Toeplitz MFMA GEMM.
//   out[t] = sum_s g[s] * xe[t + s],  g = autocorr(k) (bf16, hi only)
// Round 10: B-fragment register ping-pong. R9's per-step critical path was
// ds_read_b128 -> lgkm wait -> MFMA; now step Qr+1's 4 B-frags are read
// from LDS during step Qr's MFMA burst (intra-chunk only -- cross-chunk
// prefetch would race the async staging). Step 0 of each chunk pays the
// one remaining lgkm wait (9 per 72 steps). +16 VGPR, still spill-free.

#define T_LEN   131072
#define XE_LEN  139776
#define XE_U4   (XE_LEN / 8)      // 17472 uint4 per row
#define QQ      72                // Q-steps per wave (per Q-quarter)
#define NCH     9                 // chunks per wave
#define GP_STRIDE 24576           // bytes per gpad copy

typedef float  f32x4  __attribute__((ext_vector_type(4)));
typedef __bf16 bf16x8 __attribute__((ext_vector_type(8)));

// ---------- ws layout (bytes) ----------
#define WS_KZ   0                 // 12288 floats (zero-padded k)
#define WS_G    49152             // 8192 floats  (autocorrelation)
#define WS_GP   81920             // 2 copies x 24576 B bf16 gpad
#define WS_XE   131072            // 32*139776 bf16 padded signal
#define WS_END  9347072

__device__ __forceinline__ void gload_lds16(const uint4* g, uint4* lds) {
  __builtin_amdgcn_global_load_lds(
      (const __attribute__((address_space(1))) unsigned int*)g,
      (__attribute__((address_space(3))) unsigned int*)lds, 16, 0, 0);
}

// K1: g[s] += partial over 256-long i-chunk; grid (32, 16).
__global__ void k_autocorr(const float* __restrict__ k,
                           const float* __restrict__ kz,
                           float* __restrict__ g) {
  int s = blockIdx.x * 256 + threadIdx.x;
  int i0 = blockIdx.y * 256;
  const float* kk  = k + i0;
  const float* kzs = kz + (8191 - s) + i0;   // 4-B aligned only
  float a0 = 0.f, a1 = 0.f, a2 = 0.f, a3 = 0.f;
  #pragma unroll 4
  for (int i = 0; i < 256; i += 4) {
    float4 kv = *(const float4*)(kk + i);
    float4 zv;
    __builtin_memcpy(&zv, kzs + i, 16);
    a0 = fmaf(kv.x, zv.x, a0);
    a1 = fmaf(kv.y, zv.y, a1);
    a2 = fmaf(kv.z, zv.z, a2);
    a3 = fmaf(kv.w, zv.w, a3);
  }
  atomicAdd(&g[s], (a0 + a1) + (a2 + a3));
}

// K2': gpad[e] = bf16(g[e]) for e in [0,8190], else 0, over e in
// [-1024, 10240); TWO copies byte-shifted by GP_STRIDE+2 so every lane's
// 16-B A-frag read (start element 32(F-24)+8q-n, parity = n&1) is 4-B
// aligned. Grid (44), 256 thr.
__global__ void k_build_gpad(const float* __restrict__ g,
                             char* __restrict__ gp) {
  int idx = blockIdx.x * 256 + threadIdx.x;   // [0, 11264)
  int e = idx - 1024;
  float v = (e >= 0 && e <= 8190) ? g[e] : 0.0f;
  __bf16 b = (__bf16)v;
  *(__bf16*)(gp + 2 * idx) = b;
  *(__bf16*)(gp + GP_STRIDE + 2 + 2 * idx) = b;
}

// K0 (fused): xe[row][w] = bf16( X(w-4095) ), reflect in [-2048, T+2048),
// else 0. blockIdx.y==0 additionally builds kz (zero-padded k) and zeros g.
__global__ void k_build_xe(const float* __restrict__ x, __bf16* __restrict__ xe,
                           const float* __restrict__ k, float* __restrict__ kz,
                           float* __restrict__ g) {
  if (blockIdx.y == 0) {           // fused former k_build_kz
    int m = blockIdx.x * 256 + threadIdx.x;
    if (m < 12288) {
      int i = m - 4096;
      kz[m] = (i >= 0 && i < 4096) ? k[i] : 0.0f;
    }
    if (m < 8192) g[m] = 0.0f;
  }
  int e0 = (blockIdx.x * 256 + threadIdx.x) * 8;
  int row = blockIdx.y;
  if (e0 >= XE_LEN) return;
  const float* xr = x + (size_t)row * T_LEN;
  int v0 = e0 - 4095;
  bf16x8 outv;
  if (v0 >= 0 && v0 <= T_LEN - 8) {
    float4 f0, f1;
    __builtin_memcpy(&f0, xr + v0, 16);
    __builtin_memcpy(&f1, xr + v0 + 4, 16);
    outv[0] = (__bf16)f0.x; outv[1] = (__bf16)f0.y;
    outv[2] = (__bf16)f0.z; outv[3] = (__bf16)f0.w;
    outv[4] = (__bf16)f1.x; outv[5] = (__bf16)f1.y;
    outv[6] = (__bf16)f1.z; outv[7] = (__bf16)f1.w;
  } else {
    #pragma unroll
    for (int u = 0; u < 8; ++u) {
      int v = v0 + u;
      float val = 0.0f;
      if (v >= -2048 && v < T_LEN + 2048) {
        int v2 = v < 0 ? -v : v;
        v2 = v2 >= T_LEN ? 2 * T_LEN - 2 - v2 : v2;
        val = xr[v2];
      }
      outv[u] = (__bf16)val;
    }
  }
  ((uint4*)(xe + (size_t)row * XE_LEN))[e0 >> 3] =
      __builtin_bit_cast(uint4, outv);
}

// One pipelined Q-step. BC holds this step's B-frags (read last step);
// BN receives next step's (read during this step's MFMA burst). Old ring
// values copied out, GA[Qr] refilled from L1-resident gpad (consumed next
// chunk -> latency-free).
#define QSTEP(CH, Qr, GA, GB, GC, GD, BC, BN)                              \
  {                                                                        \
    if ((Qr) < 7) {              /* prefetch next step's B from LDS */     \
      _Pragma("unroll")                                                    \
      for (int r = 0; r < 4; ++r)                                          \
        BN[r] = __builtin_bit_cast(bf16x8, bw[(r << 6) + 4 * ((Qr) + 1)]); \
    }                                                                      \
    bf16x8 a3 = GA[Qr], a2 = GB[Qr], a1 = GC[Qr], a0 = GD[Qr];             \
    uint4 tmp;                                                             \
    __builtin_memcpy(&tmp,                                                 \
        laneA + ((size_t)(Qbeg + (CH) * 8 + 32 + Qr) << 6), 16);           \
    GA[Qr] = __builtin_bit_cast(bf16x8, tmp);                              \
    __builtin_amdgcn_s_setprio(1);                                         \
    _Pragma("unroll")                                                      \
    for (int r = 0; r < 4; ++r) {                                          \
      acc[r][0] = __builtin_amdgcn_mfma_f32_16x16x32_bf16(a0, BC[r],       \
                                                          acc[r][0], 0, 0, 0); \
      acc[r][1] = __builtin_amdgcn_mfma_f32_16x16x32_bf16(a1, BC[r],       \
                                                          acc[r][1], 0, 0, 0); \
      acc[r][2] = __builtin_amdgcn_mfma_f32_16x16x32_bf16(a2, BC[r],       \
                                                          acc[r][2], 0, 0, 0); \
      acc[r][3] = __builtin_amdgcn_mfma_f32_16x16x32_bf16(a3, BC[r],       \
                                                          acc[r][3], 0, 0, 0); \
    }                                                                      \
    __builtin_amdgcn_s_setprio(0);                                         \
  }

// One chunk (8 Q-steps), ring roles GA=oldest(mt3) .. GD=newest(mt0).
// Staging of chunk CH+1 issued at top; vmcnt(0) drain at end (staging is
// 8 steps old by then). B ping-pong: step 0 reads synchronously (the one
// lgkm wait per chunk), steps 1..7 prefetched under MFMA.
#define CHUNK(CH, BUF, GA, GB, GC, GD, DO_STAGE)                           \
  {                                                                        \
    if (DO_STAGE) {                                                        \
      uint4* dst = sw + ((BUF ^ 1) << 8);                                  \
      const uint4* src = gbase + (((CH) + 1) << 5);                        \
      _Pragma("unroll")                                                    \
      for (int r = 0; r < 4; ++r)                                          \
        gload_lds16(src + (size_t)r * XE_U4, dst + (r << 6));              \
    }                                                                      \
    const uint4* bw = sw + ((BUF) << 8) + lofs;                            \
    bf16x8 B0[4], B1[4];                                                   \
    _Pragma("unroll")                                                      \
    for (int r = 0; r < 4; ++r)                                            \
      B0[r] = __builtin_bit_cast(bf16x8, bw[r << 6]);                      \
    QSTEP(CH, 0, GA, GB, GC, GD, B0, B1)                                   \
    QSTEP(CH, 1, GA, GB, GC, GD, B1, B0)                                   \
    QSTEP(CH, 2, GA, GB, GC, GD, B0, B1)                                   \
    QSTEP(CH, 3, GA, GB, GC, GD, B1, B0)                                   \
    QSTEP(CH, 4, GA, GB, GC, GD, B0, B1)                                   \
    QSTEP(CH, 5, GA, GB, GC, GD, B1, B0)                                   \
    QSTEP(CH, 6, GA, GB, GC, GD, B0, B1)                                   \
    QSTEP(CH, 7, GA, GB, GC, GD, B1, B0)                                   \
    if (DO_STAGE)                                                          \
      asm volatile("s_waitcnt vmcnt(0)" ::: "memory");                     \
  }

// Main: 512 threads = 8 waves = 2 row-groups (4 rows) x 4 Q-quarters.
// Per Q-step: 1 fresh A load (gpad, L1), 4 ds_read_b128 (B, prefetched
// one step ahead), 16 MFMA. Ring G0..G3 rotates roles every chunk.
// No barriers in the main loop.
__global__ __launch_bounds__(512, 2) void k_fir_mfma(
    const uint4* __restrict__ xeu, const char* __restrict__ gpad,
    float* __restrict__ out) {
  __shared__ uint4 sbB[4096];      // 64 KB: wave*512 + buf*256 + row*64

  const int tid = threadIdx.x;
  const int w   = tid >> 6;                  // 8 waves
  const int l   = tid & 63;
  const int q   = l >> 4;
  const int n   = l & 15;
  const int qh  = w & 3;                     // Q-quarter
  const int rg  = w >> 2;                    // row-group (4 rows)

  // XCD swizzle: 512 blocks, 8 XCDs -> 64 contiguous flat ids per XCD.
  const int orig = blockIdx.x;
  const int flat = (orig & 7) * 64 + (orig >> 3);
  const int bx   = flat & 127;
  const int by   = flat >> 7;

  const int t0     = bx << 10;               // 1024 outputs per block
  const int brbase = by << 3;                // block's 8 rows
  const int wrbase = brbase + (rg << 2);     // this wave's 4 rows
  const int Qbeg   = qh * QQ;
  const int lofs   = q + 2 * n;              // uint4 offset in B window

  // per-lane global base for staging (lane l covers uint4 slot l of a row)
  const uint4* gbase = xeu + (size_t)wrbase * XE_U4 + (t0 >> 3) + 4 * Qbeg + l;
  uint4* sw = sbB + (w << 9);                // 512 uint4 per wave

  // A-frag source: element e0(F) = 32(F-24) + 8q - n, byte = 2(e0+1024)
  // in copy (n&1): laneA + 64F with laneA = copy_base + 16q - 2n + 512.
  const char* laneA = gpad + ((n & 1) ? (GP_STRIDE + 2) : 0)
                      + 16 * q - 2 * n + 512;

  f32x4 acc[4][4];
  #pragma unroll
  for (int r = 0; r < 4; ++r)
    #pragma unroll
    for (int m = 0; m < 4; ++m) acc[r][m] = (f32x4){0.f, 0.f, 0.f, 0.f};

  // prologue: prime ring with frags Qbeg..Qbeg+31; stage chunk 0; drain.
  bf16x8 G0[8], G1[8], G2[8], G3[8];
  #pragma unroll
  for (int j = 0; j < 8; ++j) {
    uint4 u0, u1, u2, u3;
    __builtin_memcpy(&u0, laneA + ((size_t)(Qbeg + j) << 6), 16);
    __builtin_memcpy(&u1, laneA + ((size_t)(Qbeg + 8 + j) << 6), 16);
    __builtin_memcpy(&u2, laneA + ((size_t)(Qbeg + 16 + j) << 6), 16);
    __builtin_memcpy(&u3, laneA + ((size_t)(Qbeg + 24 + j) << 6), 16);
    G0[j] = __builtin_bit_cast(bf16x8, u0);
    G1[j] = __builtin_bit_cast(bf16x8, u1);
    G2[j] = __builtin_bit_cast(bf16x8, u2);
    G3[j] = __builtin_bit_cast(bf16x8, u3);
  }
  #pragma unroll
  for (int r = 0; r < 4; ++r)
    gload_lds16(gbase + (size_t)r * XE_U4, sw + (r << 6));
  asm volatile("s_waitcnt vmcnt(0)" ::: "memory");

  CHUNK(0, 0, G0, G1, G2, G3, 1)
  CHUNK(1, 1, G1, G2, G3, G0, 1)
  CHUNK(2, 0, G2, G3, G0, G1, 1)
  CHUNK(3, 1, G3, G0, G1, G2, 1)
  CHUNK(4, 0, G0, G1, G2, G3, 1)
  CHUNK(5, 1, G1, G2, G3, G0, 1)
  CHUNK(6, 0, G2, G3, G0, G1, 1)
  CHUNK(7, 1, G3, G0, G1, G2, 1)
  CHUNK(8, 0, G0, G1, G2, G3, 0)

  // ---- combine 4 qh partials per row-group in LDS (phased mt slices) ----
  __syncthreads();
  float* C = (float*)sbB;                    // 8 rows x 1024 t (32 KB)
  const int co = (q << 2) + (n << 4);        // C/D: col=n, row=(q*4+reg)
  #pragma unroll
  for (int ph = 0; ph < 4; ++ph) {
    const int mt = (qh + ph) & 3;
    float* cp = C + ((rg << 2) << 10) + (mt << 8) + co;
    if (ph == 0) {
      #pragma unroll
      for (int r = 0; r < 4; ++r)
        *(f32x4*)(cp + (r << 10)) = acc[r][mt];
    } else {
      #pragma unroll
      for (int r = 0; r < 4; ++r) {
        f32x4 v = *(f32x4*)(cp + (r << 10));
        v += acc[r][mt];
        *(f32x4*)(cp + (r << 10)) = v;
      }
    }
    __syncthreads();
  }

  // ---- coalesced store: 2048 f32x4, 512 threads x 4 ----
  #pragma unroll
  for (int u = 0; u < 4; ++u) {
    const int idx = tid + (u << 9);
    f32x4 v = ((f32x4*)C)[idx];
    const int row = idx >> 8;                // 256 f32x4 per row
    const int tc  = (idx & 255) << 2;
    *(f32x4*)(out + (size_t)(brbase + row) * T_LEN + t0 + tc) = v;
  }
}

extern "C" void kernel_launch(void* const* d_in, const int* in_sizes, int n_in,
                              void* d_out, int out_size, void* d_ws, size_t ws_size,
                              hipStream_t stream) {
  const float* x = (const float*)d_in[0];
  const float* k = (const float*)d_in[1];
  float* out = (float*)d_out;
  char* ws = (char*)d_ws;
  if (ws_size < (size_t)WS_END) return;

  float* kz = (float*)(ws + WS_KZ);
  float* g  = (float*)(ws + WS_G);
  char*  gp = ws + WS_GP;
  __bf16* xe = (__bf16*)(ws + WS_XE);

  k_build_xe<<<dim3((XE_LEN / 8 + 255) / 256, 32), dim3(256), 0, stream>>>(
      x, xe, k, kz, g);
  k_autocorr<<<dim3(32, 16), dim3(256), 0, stream>>>(k, kz, g);
  k_build_gpad<<<dim3(44), dim3(256), 0, stream>>>(g, gp);
  k_fir_mfma<<<dim3(512), dim3(512), 0, stream>>>(
      (const uint4*)xe, gp, out);
}